// Round 14
// baseline (210.360 us; speedup 1.0000x reference)
//
#include <hip/hip_runtime.h>

#define N_NODES 50000
#define N_EDGES 800000
#define IN_DIM  128
#define HID_DIM 128
#define OUT_DIM 64

#define NPAD 50176                          // N_NODES rounded up
#define NB 7                                // src buckets of 8192 nodes (src>>13)
#define KEYS (N_NODES * NB)                 // 350000 composite (dst,bucket) keys
#define KPAD 350208                         // 342 * 1024
#define NB_SCAN2 (KPAD / 1024)              // 342
#define ZEROB (KPAD / 1024)                 // 342 zero blocks (256 thr x int4)
#define HISTB ((N_EDGES / 4 + 255) / 256)   // 782 rank_hist blocks
#define GEMM1B ((N_NODES + 63) / 64)        // 782 gemm1 blocks
#define FILLB ((N_EDGES / 4 + 255) / 256)   // 782 fill blocks
#define DINVB ((N_NODES + 1023) / 1024)     // 49 dinv blocks (1024 thr)

typedef __attribute__((ext_vector_type(8))) short bf16x8;   // 8 bf16 in 4 VGPRs
typedef __attribute__((ext_vector_type(4))) float f32x4;

// float -> bf16 (round-to-nearest-even), as ushort
__device__ __forceinline__ unsigned short f2bf(float f) {
    unsigned u = __float_as_uint(f);
    u += 0x7fffu + ((u >> 16) & 1u);
    return (unsigned short)(u >> 16);
}
// bf16 pair unpack from a uint (little-endian: low ushort first)
__device__ __forceinline__ float bflo(unsigned u) { return __uint_as_float(u << 16); }
__device__ __forceinline__ float bfhi(unsigned u) { return __uint_as_float(u & 0xffff0000u); }

// acc[8] += nrm * unpack8(u)   (fma — same inst count as the old add path)
#define ACC8N(u, nrm)  do { \
    acc[0] = fmaf(nrm, bflo(u.x), acc[0]); acc[1] = fmaf(nrm, bfhi(u.x), acc[1]); \
    acc[2] = fmaf(nrm, bflo(u.y), acc[2]); acc[3] = fmaf(nrm, bfhi(u.y), acc[3]); \
    acc[4] = fmaf(nrm, bflo(u.z), acc[4]); acc[5] = fmaf(nrm, bfhi(u.z), acc[5]); \
    acc[6] = fmaf(nrm, bflo(u.w), acc[6]); acc[7] = fmaf(nrm, bfhi(u.w), acc[7]); } while (0)

#define ACC8(u)  do { \
    acc[0] += bflo(u.x); acc[1] += bfhi(u.x); \
    acc[2] += bflo(u.y); acc[3] += bfhi(u.y); \
    acc[4] += bflo(u.z); acc[5] += bfhi(u.z); \
    acc[6] += bflo(u.w); acc[7] += bfhi(u.w); } while (0)

// ---------------- dispatch 1: zero cnt2 + W1^T/W2^T bf16 prep ----------------

__global__ void init_kernel(int* __restrict__ cnt2,
                            const float* __restrict__ W1, const float* __restrict__ W2,
                            unsigned short* __restrict__ w1t, unsigned short* __restrict__ w2t) {
    int bid = blockIdx.x;
    if (bid < ZEROB) {
        int i = (bid * 256 + threadIdx.x) * 4;
        *(int4*)(cnt2 + i) = make_int4(0, 0, 0, 0);      // KPAD % 1024 == 0
    } else if (bid < ZEROB + 16) {
        // W1T[c][k] = bf16(W1[k][c]); 128x128 -> 4096 ushort4
        int idx = (bid - ZEROB) * 256 + threadIdx.x;
        int c = idx >> 5, k4 = (idx & 31) * 4;
        ushort4 o;
        o.x = f2bf(W1[(k4 + 0) * 128 + c]);
        o.y = f2bf(W1[(k4 + 1) * 128 + c]);
        o.z = f2bf(W1[(k4 + 2) * 128 + c]);
        o.w = f2bf(W1[(k4 + 3) * 128 + c]);
        *(ushort4*)(w1t + c * 128 + k4) = o;
    } else {
        // W2T[c][k] = bf16(W2[k][c]); 64x128 -> 2048 ushort4 (8 blocks exactly)
        int idx = (bid - ZEROB - 16) * 256 + threadIdx.x;
        int c = idx >> 5, k4 = (idx & 31) * 4;
        ushort4 o;
        o.x = f2bf(W2[(k4 + 0) * 64 + c]);
        o.y = f2bf(W2[(k4 + 1) * 64 + c]);
        o.z = f2bf(W2[(k4 + 2) * 64 + c]);
        o.w = f2bf(W2[(k4 + 3) * 64 + c]);
        *(ushort4*)(w2t + c * 128 + k4) = o;
    }
}

// ---------------- dispatch 2: rank_hist + GEMM1 (independent -> overlapped) --------
// rank_hist is atomic-latency-bound (VALU/MFMA idle); gemm1 (MFMA + loads) hides
// under it. gemm1 has no graph dependency: h1b is stored UNNORMALIZED (dinv[src]
// rides in the CSR payload instead).

__global__ __launch_bounds__(256) void hist_gemm1_kernel(const int* __restrict__ src,
                                                         const int* __restrict__ dst,
                                                         int* __restrict__ cnt2,
                                                         int* __restrict__ rank,
                                                         const float* __restrict__ x,
                                                         const unsigned short* __restrict__ w1t,
                                                         unsigned short* __restrict__ h1b) {
    int bid = blockIdx.x;
    if (bid < HISTB) {
        int e = (bid * 256 + threadIdx.x) * 4;
        if (e >= N_EDGES) return;                 // N_EDGES % 4 == 0
        int4 s4 = *(const int4*)(src + e);
        int4 d4 = *(const int4*)(dst + e);
        int k0 = d4.x * NB + (s4.x >> 13);
        int k1 = d4.y * NB + (s4.y >> 13);
        int k2 = d4.z * NB + (s4.z >> 13);
        int k3 = d4.w * NB + (s4.w >> 13);
        int r0 = atomicAdd(&cnt2[k0], 1);
        int r1 = atomicAdd(&cnt2[k1], 1);
        int r2 = atomicAdd(&cnt2[k2], 1);
        int r3 = atomicAdd(&cnt2[k3], 1);
        *(int4*)(rank + e) = make_int4(r0, r1, r2, r3);
        return;
    }

    // ---- GEMM1 (MFMA, inline fp32->bf16 A-cast): h1b = bf16(x @ W1)  [unnormalized]
    int gb = bid - HISTB;
    int wave = threadIdx.x >> 6;
    int lane = threadIdx.x & 63;
    int n = lane & 15, quad = lane >> 4;
    int row0 = gb * 64 + wave * 16;

    int arow = row0 + n;
    if (arow >= N_NODES) arow = N_NODES - 1;             // clamp (stores guarded)
    const float* aptr = x + (size_t)arow * 128 + quad * 8;
    const unsigned short* bbase = w1t + (size_t)n * 128 + quad * 8;

    f32x4 acc[8];
#pragma unroll
    for (int t = 0; t < 8; ++t) acc[t] = (f32x4){0.f, 0.f, 0.f, 0.f};

#pragma unroll
    for (int w4 = 0; w4 < 4; ++w4) {
        float4 f0 = *(const float4*)(aptr + w4 * 32);
        float4 f1 = *(const float4*)(aptr + w4 * 32 + 4);
        bf16x8 af;
        af[0] = (short)f2bf(f0.x); af[1] = (short)f2bf(f0.y);
        af[2] = (short)f2bf(f0.z); af[3] = (short)f2bf(f0.w);
        af[4] = (short)f2bf(f1.x); af[5] = (short)f2bf(f1.y);
        af[6] = (short)f2bf(f1.z); af[7] = (short)f2bf(f1.w);
#pragma unroll
        for (int t = 0; t < 8; ++t) {
            bf16x8 bf = *(const bf16x8*)(bbase + (size_t)t * 2048 + w4 * 32);
            acc[t] = __builtin_amdgcn_mfma_f32_16x16x32_bf16(af, bf, acc[t], 0, 0, 0);
        }
    }

#pragma unroll
    for (int r = 0; r < 4; ++r) {
        int row = row0 + quad * 4 + r;
        if (row < N_NODES) {
            unsigned short* o = h1b + (size_t)row * 128 + n;
#pragma unroll
            for (int t = 0; t < 8; ++t) o[t * 16] = f2bf(acc[t][r]);
        }
    }
}

// ---------------- dispatch 3: segment-reduce + dinv (both need only cnt2) ----------

__global__ __launch_bounds__(1024) void reduce_dinv_kernel(const int* __restrict__ cnt2,
                                                           int* __restrict__ blockSums,
                                                           float* __restrict__ dinv) {
    int bid = blockIdx.x;
    if (bid < NB_SCAN2) {
        __shared__ int s[1024];
        int i = bid * 1024 + threadIdx.x;
        s[threadIdx.x] = (i < KEYS) ? cnt2[i] : 0;
        __syncthreads();
        for (int off = 512; off > 0; off >>= 1) {
            if (threadIdx.x < off) s[threadIdx.x] += s[threadIdx.x + off];
            __syncthreads();
        }
        if (threadIdx.x == 0) blockSums[bid] = s[0];
    } else {
        int d = (bid - NB_SCAN2) * 1024 + threadIdx.x;
        if (d < N_NODES) {
            int base = d * NB;
            int deg = cnt2[base] + cnt2[base + 1] + cnt2[base + 2] + cnt2[base + 3]
                    + cnt2[base + 4] + cnt2[base + 5] + cnt2[base + 6];
            dinv[d] = (deg > 0) ? rsqrtf((float)deg) : 0.0f;
        }
    }
}

// ---------------- dispatch 4: exclusive scan of cnt2 -> rs (+ sentinel) ----------

__global__ __launch_bounds__(1024) void scan_kernel(const int* __restrict__ cnt2,
                                                    const int* __restrict__ blockSums,
                                                    int* __restrict__ rs) {
    __shared__ int s[1024];
    __shared__ int sums[NB_SCAN2];
    __shared__ int base_s;
    if (threadIdx.x < NB_SCAN2) sums[threadIdx.x] = blockSums[threadIdx.x];
    if (blockIdx.x == 0 && threadIdx.x == 0) rs[KEYS] = N_EDGES;   // sentinel
    int i = blockIdx.x * 1024 + threadIdx.x;
    int v = (i < KEYS) ? cnt2[i] : 0;
    s[threadIdx.x] = v;
    __syncthreads();
    if (threadIdx.x == 0) {
        int run = 0;
        for (int b = 0; b < (int)blockIdx.x; ++b) run += sums[b];
        base_s = run;
    }
    for (int off = 1; off < 1024; off <<= 1) {
        int t = (threadIdx.x >= off) ? s[threadIdx.x - off] : 0;
        __syncthreads();
        s[threadIdx.x] += t;
        __syncthreads();
    }
    if (i < KEYS) rs[i] = base_s + s[threadIdx.x] - v;           // exclusive
}

// ---------------- dispatch 5: fill CSR (atomic-free): (src, dinv[src]) pairs --------

__global__ void fill_kernel(const int* __restrict__ src, const int* __restrict__ dst,
                            const int* __restrict__ rank, const int* __restrict__ rs,
                            const float* __restrict__ dinv, int2* __restrict__ csr2) {
    int e = (blockIdx.x * 256 + threadIdx.x) * 4;
    if (e >= N_EDGES) return;
    int4 s4 = *(const int4*)(src + e);
    int4 d4 = *(const int4*)(dst + e);
    int4 r4 = *(const int4*)(rank + e);
    csr2[rs[d4.x * NB + (s4.x >> 13)] + r4.x] = make_int2(s4.x, __float_as_int(dinv[s4.x]));
    csr2[rs[d4.y * NB + (s4.y >> 13)] + r4.y] = make_int2(s4.y, __float_as_int(dinv[s4.y]));
    csr2[rs[d4.z * NB + (s4.z >> 13)] + r4.z] = make_int2(s4.z, __float_as_int(dinv[s4.z]));
    csr2[rs[d4.w * NB + (s4.w >> 13)] + r4.w] = make_int2(s4.w, __float_as_int(dinv[s4.w]));
}

// ---------------- dispatch 6: fused agg1 + GEMM2 (r10 shape) ----------------
// Phase 1: 16 lanes/node, 4 nodes concurrently per wave, 4-edge unroll
// (r10's best-measured shape). Per-edge norm = dinv[src] from csr2 (fma).
// Phase 2: 16x64 MFMA from LDS. h2b stored WITH dinv[row] fold (agg2 unchanged).

#define A1T_STRIDE 136

__global__ __launch_bounds__(256) void agg1_gemm2_fused(const int2* __restrict__ csr2,
                                                        const int* __restrict__ rs,
                                                        const float* __restrict__ dinv,
                                                        const float* __restrict__ b1,
                                                        const unsigned short* __restrict__ h1b,
                                                        const unsigned short* __restrict__ w2t,
                                                        unsigned short* __restrict__ h2b) {
    __shared__ unsigned short a1t[16 * A1T_STRIDE];      // 16 x 128 bf16, padded

    int node0 = blockIdx.x * 16;
    int g = threadIdx.x >> 4;        // node within block
    int q = threadIdx.x & 15;        // uint4 slot (channels 8q..8q+7)
    int node = node0 + g;            // always < N_NODES (50000 = 3125*16)
    int start = rs[node * NB];
    int m = rs[node * NB + NB] - start;   // sentinel rs[KEYS] covers node = N-1

    float acc[8] = {};
    int j = 0;
    for (; j + 3 < m; j += 4) {
        int2 p0 = csr2[start + j];
        int2 p1 = csr2[start + j + 1];
        int2 p2 = csr2[start + j + 2];
        int2 p3 = csr2[start + j + 3];
        uint4 u0 = ((const uint4*)(h1b + (size_t)p0.x * 128))[q];
        uint4 u1 = ((const uint4*)(h1b + (size_t)p1.x * 128))[q];
        uint4 u2 = ((const uint4*)(h1b + (size_t)p2.x * 128))[q];
        uint4 u3 = ((const uint4*)(h1b + (size_t)p3.x * 128))[q];
        float n0 = __int_as_float(p0.y), n1 = __int_as_float(p1.y);
        float n2 = __int_as_float(p2.y), n3 = __int_as_float(p3.y);
        ACC8N(u0, n0); ACC8N(u1, n1); ACC8N(u2, n2); ACC8N(u3, n3);
    }
    for (; j < m; ++j) {
        int2 p0 = csr2[start + j];
        uint4 u0 = ((const uint4*)(h1b + (size_t)p0.x * 128))[q];
        float n0 = __int_as_float(p0.y);
        ACC8N(u0, n0);
    }

    {
        float dn = dinv[node];
        float4 bA = ((const float4*)b1)[2 * q];
        float4 bB = ((const float4*)b1)[2 * q + 1];
        ushort4 oA, oB;
        oA.x = f2bf(fmaxf(acc[0] * dn + bA.x, 0.f));
        oA.y = f2bf(fmaxf(acc[1] * dn + bA.y, 0.f));
        oA.z = f2bf(fmaxf(acc[2] * dn + bA.z, 0.f));
        oA.w = f2bf(fmaxf(acc[3] * dn + bA.w, 0.f));
        oB.x = f2bf(fmaxf(acc[4] * dn + bB.x, 0.f));
        oB.y = f2bf(fmaxf(acc[5] * dn + bB.y, 0.f));
        oB.z = f2bf(fmaxf(acc[6] * dn + bB.z, 0.f));
        oB.w = f2bf(fmaxf(acc[7] * dn + bB.w, 0.f));
        ushort4* o = (ushort4*)(a1t + g * A1T_STRIDE + q * 8);
        o[0] = oA;
        o[1] = oB;
    }
    __syncthreads();

    // Phase 2: MFMA 16 rows x 16 cols per wave
    int wave = threadIdx.x >> 6;
    int lane = threadIdx.x & 63;
    int n = lane & 15, quad = lane >> 4;
    const unsigned short* bbase = w2t + (size_t)(wave * 16 + n) * 128 + quad * 8;
    const unsigned short* abase = a1t + (size_t)n * A1T_STRIDE + quad * 8;

    f32x4 c2 = (f32x4){0.f, 0.f, 0.f, 0.f};
#pragma unroll
    for (int w4 = 0; w4 < 4; ++w4) {
        bf16x8 af = *(const bf16x8*)(abase + w4 * 32);
        bf16x8 bf = *(const bf16x8*)(bbase + w4 * 32);
        c2 = __builtin_amdgcn_mfma_f32_16x16x32_bf16(af, bf, c2, 0, 0, 0);
    }

#pragma unroll
    for (int r = 0; r < 4; ++r) {
        int row = node0 + quad * 4 + r;
        float dn = dinv[row];
        h2b[(size_t)row * 64 + wave * 16 + n] = f2bf(c2[r] * dn);
    }
}

// ---------------- dispatch 7: agg2: out[n] = b2 + dinv[n] * sum h2b[src_e] ----------
// h2b already carries dinv[src]; csr2's norm field unused here.

__global__ __launch_bounds__(256) void agg2_kernel(const int2* __restrict__ csr2,
                                                   const int* __restrict__ rs,
                                                   const float* __restrict__ dinv,
                                                   const float* __restrict__ b2,
                                                   const unsigned short* __restrict__ h2b,
                                                   float* __restrict__ out) {
    int node = blockIdx.x * 4 + (threadIdx.x >> 6);
    if (node >= N_NODES) return;
    int lane = threadIdx.x & 63;
    int grp = lane >> 3;         // 8 groups: edge j = grp + 8t
    int q   = lane & 7;          // uint4 slot (channels 8q..8q+7)
    int start = rs[node * NB];
    int m = rs[node * NB + NB] - start;

    float acc[8] = {};

    int j = grp;
    for (; j + 8 < m; j += 16) {
        int s0 = csr2[start + j].x;
        int s1 = csr2[start + j + 8].x;
        uint4 u0 = ((const uint4*)(h2b + (size_t)s0 * 64))[q];
        uint4 u1 = ((const uint4*)(h2b + (size_t)s1 * 64))[q];
        ACC8(u0); ACC8(u1);
    }
    if (j < m) {
        int s0 = csr2[start + j].x;
        uint4 u0 = ((const uint4*)(h2b + (size_t)s0 * 64))[q];
        ACC8(u0);
    }

#pragma unroll
    for (int d = 8; d <= 32; d <<= 1) {
#pragma unroll
        for (int c = 0; c < 8; ++c) acc[c] += __shfl_xor(acc[c], d, 64);
    }

    if (lane < 8) {
        float dn = dinv[node];
        float4 bA = ((const float4*)b2)[2 * q];
        float4 bB = ((const float4*)b2)[2 * q + 1];
        float4 rA, rB;
        rA.x = acc[0] * dn + bA.x;
        rA.y = acc[1] * dn + bA.y;
        rA.z = acc[2] * dn + bA.z;
        rA.w = acc[3] * dn + bA.w;
        rB.x = acc[4] * dn + bB.x;
        rB.y = acc[5] * dn + bB.y;
        rB.z = acc[6] * dn + bB.z;
        rB.w = acc[7] * dn + bB.w;
        float4* o = (float4*)(out + (size_t)node * 64);
        o[2 * q] = rA;
        o[2 * q + 1] = rB;
    }
}

// ---------------- launch ----------------

extern "C" void kernel_launch(void* const* d_in, const int* in_sizes, int n_in,
                              void* d_out, int out_size, void* d_ws, size_t ws_size,
                              hipStream_t stream) {
    const float* x  = (const float*)d_in[0];
    const int*   ei = (const int*)d_in[1];       // [2, E]: src = ei[0..E), dst = ei[E..2E)
    const float* W1 = (const float*)d_in[2];
    const float* b1 = (const float*)d_in[3];
    const float* W2 = (const float*)d_in[4];
    const float* b2 = (const float*)d_in[5];
    float* out = (float*)d_out;

    const int* src = ei;
    const int* dst = ei + N_EDGES;

    // workspace layout (16B-aligned regions; csr2 offset is even -> 8B aligned)
    char* ws = (char*)d_ws;
    int*   cnt2      = (int*)ws;                                 // KPAD
    int*   rs        = cnt2 + KPAD;                              // KPAD (>= KEYS+1)
    int*   blockSums = rs + KPAD;                                // 384
    float* dinv      = (float*)(blockSums + 384);                // NPAD
    int*   rank      = (int*)(dinv + NPAD);                      // N_EDGES
    int2*  csr2      = (int2*)(rank + N_EDGES);                  // N_EDGES int2
    unsigned short* h1b = (unsigned short*)(csr2 + N_EDGES);     // 50000*128 bf16
    unsigned short* h2b = h1b + (size_t)N_NODES * HID_DIM;       // 50000*64 bf16
    unsigned short* w1t = h2b + (size_t)N_NODES * OUT_DIM;       // 128*128 bf16
    unsigned short* w2t = w1t + 128 * 128;                       // 64*128 bf16

    // 1. zero cnt2 + W1^T/W2^T prep
    init_kernel<<<ZEROB + 24, 256, 0, stream>>>(cnt2, W1, W2, w1t, w2t);

    // 2. rank+histogram + GEMM1 (independent halves overlapped; gemm1 hides under
    //    rank_hist's atomic latency)
    hist_gemm1_kernel<<<HISTB + GEMM1B, 256, 0, stream>>>(src, dst, cnt2, rank, x, w1t, h1b);

    // 3. segment-reduce + dinv
    reduce_dinv_kernel<<<NB_SCAN2 + DINVB, 1024, 0, stream>>>(cnt2, blockSums, dinv);

    // 4. exclusive scan cnt2 -> rs (+ sentinel)
    scan_kernel<<<NB_SCAN2, 1024, 0, stream>>>(cnt2, blockSums, rs);

    // 5. fill CSR: (src, dinv[src]) pairs, atomic-free
    fill_kernel<<<FILLB, 256, 0, stream>>>(src, dst, rank, rs, dinv, csr2);

    // 6. fused: a1 = relu(b1 + dinv_d * sum(dinv_s * h1b[s]));  h2b = bf16(dinv*(a1 @ W2))
    agg1_gemm2_fused<<<N_NODES / 16, 256, 0, stream>>>(csr2, rs, dinv, b1, h1b, w2t, h2b);

    // 7. out = b2 + dinv * gather(h2b)
    agg2_kernel<<<(N_NODES + 3) / 4, 256, 0, stream>>>(csr2, rs, dinv, b2, h2b, out);
}

// Round 15
// 207.183 us; speedup vs baseline: 1.0153x; 1.0153x over previous
//
#include <hip/hip_runtime.h>

#define N_NODES 50000
#define N_EDGES 800000
#define IN_DIM  128
#define HID_DIM 128
#define OUT_DIM 64

#define NPAD 50176                          // N_NODES rounded up
#define NB 7                                // src buckets of 8192 nodes (src>>13)
#define KEYS (N_NODES * NB)                 // 350000 composite (dst,bucket) keys
#define KPAD 350208                         // 342 * 1024
#define NB_SCAN2 (KPAD / 1024)              // 342
#define FILLB ((N_EDGES / 4 + 255) / 256)   // 782 fill blocks
#define GEMM1B ((N_NODES + 63) / 64)        // 782 gemm1 blocks
#define DINVB ((N_NODES + 1023) / 1024)     // 49 dinv blocks (1024 thr)

typedef __attribute__((ext_vector_type(8))) short bf16x8;   // 8 bf16 in 4 VGPRs
typedef __attribute__((ext_vector_type(4))) float f32x4;

// float -> bf16 (round-to-nearest-even), as ushort
__device__ __forceinline__ unsigned short f2bf(float f) {
    unsigned u = __float_as_uint(f);
    u += 0x7fffu + ((u >> 16) & 1u);
    return (unsigned short)(u >> 16);
}
// bf16 pair unpack from a uint (little-endian: low ushort first)
__device__ __forceinline__ float bflo(unsigned u) { return __uint_as_float(u << 16); }
__device__ __forceinline__ float bfhi(unsigned u) { return __uint_as_float(u & 0xffff0000u); }

// accumulate one uint4 (8 bf16) into acc[8]
#define ACC8(u)  do { \
    acc[0] += bflo(u.x); acc[1] += bfhi(u.x); \
    acc[2] += bflo(u.y); acc[3] += bfhi(u.y); \
    acc[4] += bflo(u.z); acc[5] += bfhi(u.z); \
    acc[6] += bflo(u.w); acc[7] += bfhi(u.w); } while (0)

// ---------------- dispatch 2: rank+histogram, 1 edge/thread ----------------
// r14 lesson: the atomic-with-return chain is the bottleneck. 1 edge/thread gives
// 800k independent depth-1 chains (was 200k depth-4 chains) — 4x the MLP on the
// atomic pipe. Loads and the rank store stay coalesced.

__global__ void rank_hist_kernel(const int* __restrict__ src, const int* __restrict__ dst,
                                 int* __restrict__ cnt2, int* __restrict__ rank) {
    int e = blockIdx.x * 256 + threadIdx.x;
    if (e >= N_EDGES) return;
    int s = src[e], d = dst[e];
    rank[e] = atomicAdd(&cnt2[d * NB + (s >> 13)], 1);
}

// ---------------- dispatch 3: segment-reduce + dinv (from cnt2) + W^T prep ----------

__global__ __launch_bounds__(1024) void prep_kernel(const int* __restrict__ cnt2,
                                                    int* __restrict__ blockSums,
                                                    float* __restrict__ dinv,
                                                    const float* __restrict__ W1,
                                                    const float* __restrict__ W2,
                                                    unsigned short* __restrict__ w1t,
                                                    unsigned short* __restrict__ w2t) {
    int bid = blockIdx.x;
    if (bid < NB_SCAN2) {
        __shared__ int s[1024];
        int i = bid * 1024 + threadIdx.x;
        s[threadIdx.x] = (i < KEYS) ? cnt2[i] : 0;
        __syncthreads();
        for (int off = 512; off > 0; off >>= 1) {
            if (threadIdx.x < off) s[threadIdx.x] += s[threadIdx.x + off];
            __syncthreads();
        }
        if (threadIdx.x == 0) blockSums[bid] = s[0];
    } else if (bid < NB_SCAN2 + DINVB) {
        int d = (bid - NB_SCAN2) * 1024 + threadIdx.x;
        if (d < N_NODES) {
            int base = d * NB;
            int deg = cnt2[base] + cnt2[base + 1] + cnt2[base + 2] + cnt2[base + 3]
                    + cnt2[base + 4] + cnt2[base + 5] + cnt2[base + 6];
            dinv[d] = (deg > 0) ? rsqrtf((float)deg) : 0.0f;
        }
    } else if (bid < NB_SCAN2 + DINVB + 4) {
        // W1T[c][k] = bf16(W1[k][c]); 128x128 -> 4096 ushort4
        int idx = (bid - NB_SCAN2 - DINVB) * 1024 + threadIdx.x;
        int c = idx >> 5, k4 = (idx & 31) * 4;
        ushort4 o;
        o.x = f2bf(W1[(k4 + 0) * 128 + c]);
        o.y = f2bf(W1[(k4 + 1) * 128 + c]);
        o.z = f2bf(W1[(k4 + 2) * 128 + c]);
        o.w = f2bf(W1[(k4 + 3) * 128 + c]);
        *(ushort4*)(w1t + c * 128 + k4) = o;
    } else {
        // W2T[c][k] = bf16(W2[k][c]); 64x128 -> 2048 ushort4
        int idx = (bid - NB_SCAN2 - DINVB - 4) * 1024 + threadIdx.x;
        if (idx >= 64 * 32) return;
        int c = idx >> 5, k4 = (idx & 31) * 4;
        ushort4 o;
        o.x = f2bf(W2[(k4 + 0) * 64 + c]);
        o.y = f2bf(W2[(k4 + 1) * 64 + c]);
        o.z = f2bf(W2[(k4 + 2) * 64 + c]);
        o.w = f2bf(W2[(k4 + 3) * 64 + c]);
        *(ushort4*)(w2t + c * 128 + k4) = o;
    }
}

// ---------------- dispatch 4: exclusive scan of cnt2 -> rs (+ sentinel) ----------

__global__ __launch_bounds__(1024) void scan_kernel(const int* __restrict__ cnt2,
                                                    const int* __restrict__ blockSums,
                                                    int* __restrict__ rs) {
    __shared__ int s[1024];
    __shared__ int sums[NB_SCAN2];
    __shared__ int base_s;
    if (threadIdx.x < NB_SCAN2) sums[threadIdx.x] = blockSums[threadIdx.x];
    if (blockIdx.x == 0 && threadIdx.x == 0) rs[KEYS] = N_EDGES;   // sentinel
    int i = blockIdx.x * 1024 + threadIdx.x;
    int v = (i < KEYS) ? cnt2[i] : 0;
    s[threadIdx.x] = v;
    __syncthreads();
    if (threadIdx.x == 0) {
        int run = 0;
        for (int b = 0; b < (int)blockIdx.x; ++b) run += sums[b];
        base_s = run;
    }
    for (int off = 1; off < 1024; off <<= 1) {
        int t = (threadIdx.x >= off) ? s[threadIdx.x - off] : 0;
        __syncthreads();
        s[threadIdx.x] += t;
        __syncthreads();
    }
    if (i < KEYS) rs[i] = base_s + s[threadIdx.x] - v;           // exclusive
}

// ---------------- dispatch 5: fill CSR + GEMM1 (independent -> overlapped) --------
// fill is store-latency-bound, gemm1 MFMA-bound: compatible co-residents
// (r13 measured win; r14 showed atomics+streaming do NOT mix, but fill has no atomics).

__global__ __launch_bounds__(256) void fill_gemm1_kernel(const int* __restrict__ src,
                                                         const int* __restrict__ dst,
                                                         const int* __restrict__ rank,
                                                         const int* __restrict__ rs,
                                                         int* __restrict__ csr_src,
                                                         const float* __restrict__ x,
                                                         const unsigned short* __restrict__ w1t,
                                                         const float* __restrict__ dinv,
                                                         unsigned short* __restrict__ h1b) {
    int bid = blockIdx.x;
    if (bid < FILLB) {
        int e = (bid * 256 + threadIdx.x) * 4;
        if (e >= N_EDGES) return;
        int4 s4 = *(const int4*)(src + e);
        int4 d4 = *(const int4*)(dst + e);
        int4 r4 = *(const int4*)(rank + e);
        csr_src[rs[d4.x * NB + (s4.x >> 13)] + r4.x] = s4.x;
        csr_src[rs[d4.y * NB + (s4.y >> 13)] + r4.y] = s4.y;
        csr_src[rs[d4.z * NB + (s4.z >> 13)] + r4.z] = s4.z;
        csr_src[rs[d4.w * NB + (s4.w >> 13)] + r4.w] = s4.w;
        return;
    }

    // ---- GEMM1 (MFMA, inline fp32->bf16 A-cast): h1b = bf16(dinv * (x @ W1)) ----
    int gb = bid - FILLB;
    int wave = threadIdx.x >> 6;
    int lane = threadIdx.x & 63;
    int n = lane & 15, quad = lane >> 4;
    int row0 = gb * 64 + wave * 16;

    int arow = row0 + n;
    if (arow >= N_NODES) arow = N_NODES - 1;             // clamp (stores guarded)
    const float* aptr = x + (size_t)arow * 128 + quad * 8;
    const unsigned short* bbase = w1t + (size_t)n * 128 + quad * 8;

    f32x4 acc[8];
#pragma unroll
    for (int t = 0; t < 8; ++t) acc[t] = (f32x4){0.f, 0.f, 0.f, 0.f};

#pragma unroll
    for (int w4 = 0; w4 < 4; ++w4) {
        float4 f0 = *(const float4*)(aptr + w4 * 32);
        float4 f1 = *(const float4*)(aptr + w4 * 32 + 4);
        bf16x8 af;
        af[0] = (short)f2bf(f0.x); af[1] = (short)f2bf(f0.y);
        af[2] = (short)f2bf(f0.z); af[3] = (short)f2bf(f0.w);
        af[4] = (short)f2bf(f1.x); af[5] = (short)f2bf(f1.y);
        af[6] = (short)f2bf(f1.z); af[7] = (short)f2bf(f1.w);
#pragma unroll
        for (int t = 0; t < 8; ++t) {
            bf16x8 bf = *(const bf16x8*)(bbase + (size_t)t * 2048 + w4 * 32);
            acc[t] = __builtin_amdgcn_mfma_f32_16x16x32_bf16(af, bf, acc[t], 0, 0, 0);
        }
    }

#pragma unroll
    for (int r = 0; r < 4; ++r) {
        int row = row0 + quad * 4 + r;
        if (row < N_NODES) {
            float dn = dinv[row];
            unsigned short* o = h1b + (size_t)row * 128 + n;
#pragma unroll
            for (int t = 0; t < 8; ++t) o[t * 16] = f2bf(acc[t][r] * dn);
        }
    }
}

// ---------------- dispatch 6: fused agg1 + GEMM2 (r10 shape) ----------------

#define A1T_STRIDE 136

__global__ __launch_bounds__(256) void agg1_gemm2_fused(const int* __restrict__ csr_src,
                                                        const int* __restrict__ rs,
                                                        const float* __restrict__ dinv,
                                                        const float* __restrict__ b1,
                                                        const unsigned short* __restrict__ h1b,
                                                        const unsigned short* __restrict__ w2t,
                                                        unsigned short* __restrict__ h2b) {
    __shared__ unsigned short a1t[16 * A1T_STRIDE];      // 16 x 128 bf16, padded

    int node0 = blockIdx.x * 16;
    int g = threadIdx.x >> 4;        // node within block
    int q = threadIdx.x & 15;        // uint4 slot (channels 8q..8q+7)
    int node = node0 + g;            // always < N_NODES (50000 = 3125*16)
    int start = rs[node * NB];
    int m = rs[node * NB + NB] - start;   // sentinel rs[KEYS] covers node = N-1

    float acc[8] = {};
    int j = 0;
    for (; j + 3 < m; j += 4) {
        int s0 = csr_src[start + j];
        int s1 = csr_src[start + j + 1];
        int s2 = csr_src[start + j + 2];
        int s3 = csr_src[start + j + 3];
        uint4 u0 = ((const uint4*)(h1b + (size_t)s0 * 128))[q];
        uint4 u1 = ((const uint4*)(h1b + (size_t)s1 * 128))[q];
        uint4 u2 = ((const uint4*)(h1b + (size_t)s2 * 128))[q];
        uint4 u3 = ((const uint4*)(h1b + (size_t)s3 * 128))[q];
        ACC8(u0); ACC8(u1); ACC8(u2); ACC8(u3);
    }
    for (; j < m; ++j) {
        int s0 = csr_src[start + j];
        uint4 u0 = ((const uint4*)(h1b + (size_t)s0 * 128))[q];
        ACC8(u0);
    }

    {
        float dn = dinv[node];
        float4 bA = ((const float4*)b1)[2 * q];
        float4 bB = ((const float4*)b1)[2 * q + 1];
        ushort4 oA, oB;
        oA.x = f2bf(fmaxf(acc[0] * dn + bA.x, 0.f));
        oA.y = f2bf(fmaxf(acc[1] * dn + bA.y, 0.f));
        oA.z = f2bf(fmaxf(acc[2] * dn + bA.z, 0.f));
        oA.w = f2bf(fmaxf(acc[3] * dn + bA.w, 0.f));
        oB.x = f2bf(fmaxf(acc[4] * dn + bB.x, 0.f));
        oB.y = f2bf(fmaxf(acc[5] * dn + bB.y, 0.f));
        oB.z = f2bf(fmaxf(acc[6] * dn + bB.z, 0.f));
        oB.w = f2bf(fmaxf(acc[7] * dn + bB.w, 0.f));
        ushort4* o = (ushort4*)(a1t + g * A1T_STRIDE + q * 8);
        o[0] = oA;
        o[1] = oB;
    }
    __syncthreads();

    // Phase 2: MFMA 16 rows x 16 cols per wave
    int wave = threadIdx.x >> 6;
    int lane = threadIdx.x & 63;
    int n = lane & 15, quad = lane >> 4;
    const unsigned short* bbase = w2t + (size_t)(wave * 16 + n) * 128 + quad * 8;
    const unsigned short* abase = a1t + (size_t)n * A1T_STRIDE + quad * 8;

    f32x4 c2 = (f32x4){0.f, 0.f, 0.f, 0.f};
#pragma unroll
    for (int w4 = 0; w4 < 4; ++w4) {
        bf16x8 af = *(const bf16x8*)(abase + w4 * 32);
        bf16x8 bf = *(const bf16x8*)(bbase + w4 * 32);
        c2 = __builtin_amdgcn_mfma_f32_16x16x32_bf16(af, bf, c2, 0, 0, 0);
    }

#pragma unroll
    for (int r = 0; r < 4; ++r) {
        int row = node0 + quad * 4 + r;
        float dn = dinv[row];
        h2b[(size_t)row * 64 + wave * 16 + n] = f2bf(c2[r] * dn);
    }
}

// ---------------- dispatch 7: agg2: out[n] = b2 + dinv[n] * sum h2b[src_e] ----------

__global__ __launch_bounds__(256) void agg2_kernel(const int* __restrict__ csr_src,
                                                   const int* __restrict__ rs,
                                                   const float* __restrict__ dinv,
                                                   const float* __restrict__ b2,
                                                   const unsigned short* __restrict__ h2b,
                                                   float* __restrict__ out) {
    int node = blockIdx.x * 4 + (threadIdx.x >> 6);
    if (node >= N_NODES) return;
    int lane = threadIdx.x & 63;
    int grp = lane >> 3;         // 8 groups: edge j = grp + 8t
    int q   = lane & 7;          // uint4 slot (channels 8q..8q+7)
    int start = rs[node * NB];
    int m = rs[node * NB + NB] - start;

    float acc[8] = {};

    int j = grp;
    for (; j + 8 < m; j += 16) {
        int s0 = csr_src[start + j];
        int s1 = csr_src[start + j + 8];
        uint4 u0 = ((const uint4*)(h2b + (size_t)s0 * 64))[q];
        uint4 u1 = ((const uint4*)(h2b + (size_t)s1 * 64))[q];
        ACC8(u0); ACC8(u1);
    }
    if (j < m) {
        int s0 = csr_src[start + j];
        uint4 u0 = ((const uint4*)(h2b + (size_t)s0 * 64))[q];
        ACC8(u0);
    }

#pragma unroll
    for (int d = 8; d <= 32; d <<= 1) {
#pragma unroll
        for (int c = 0; c < 8; ++c) acc[c] += __shfl_xor(acc[c], d, 64);
    }

    if (lane < 8) {
        float dn = dinv[node];
        float4 bA = ((const float4*)b2)[2 * q];
        float4 bB = ((const float4*)b2)[2 * q + 1];
        float4 rA, rB;
        rA.x = acc[0] * dn + bA.x;
        rA.y = acc[1] * dn + bA.y;
        rA.z = acc[2] * dn + bA.z;
        rA.w = acc[3] * dn + bA.w;
        rB.x = acc[4] * dn + bB.x;
        rB.y = acc[5] * dn + bB.y;
        rB.z = acc[6] * dn + bB.z;
        rB.w = acc[7] * dn + bB.w;
        float4* o = (float4*)(out + (size_t)node * 64);
        o[2 * q] = rA;
        o[2 * q + 1] = rB;
    }
}

// ---------------- launch ----------------

extern "C" void kernel_launch(void* const* d_in, const int* in_sizes, int n_in,
                              void* d_out, int out_size, void* d_ws, size_t ws_size,
                              hipStream_t stream) {
    const float* x  = (const float*)d_in[0];
    const int*   ei = (const int*)d_in[1];       // [2, E]: src = ei[0..E), dst = ei[E..2E)
    const float* W1 = (const float*)d_in[2];
    const float* b1 = (const float*)d_in[3];
    const float* W2 = (const float*)d_in[4];
    const float* b2 = (const float*)d_in[5];
    float* out = (float*)d_out;

    const int* src = ei;
    const int* dst = ei + N_EDGES;

    // workspace layout (16B-aligned regions)
    char* ws = (char*)d_ws;
    int*   cnt2      = (int*)ws;                                 // KPAD
    int*   rs        = cnt2 + KPAD;                              // KPAD (>= KEYS+1)
    int*   blockSums = rs + KPAD;                                // 384
    float* dinv      = (float*)(blockSums + 384);                // NPAD
    int*   rank      = (int*)(dinv + NPAD);                      // N_EDGES
    int*   csr_src   = rank + N_EDGES;                           // N_EDGES
    unsigned short* h1b = (unsigned short*)(csr_src + N_EDGES);  // 50000*128 bf16
    unsigned short* h2b = h1b + (size_t)N_NODES * HID_DIM;       // 50000*64 bf16
    unsigned short* w1t = h2b + (size_t)N_NODES * OUT_DIM;       // 128*128 bf16
    unsigned short* w2t = w1t + 128 * 128;                       // 64*128 bf16

    // 1. zero cnt2
    hipMemsetAsync(cnt2, 0, KPAD * sizeof(int), stream);

    // 2. rank+histogram, 1 edge/thread (depth-1 atomic chains)
    rank_hist_kernel<<<(N_EDGES + 255) / 256, 256, 0, stream>>>(src, dst, cnt2, rank);

    // 3. segment-reduce + dinv + W1^T/W2^T prep
    prep_kernel<<<NB_SCAN2 + DINVB + 6, 1024, 0, stream>>>(cnt2, blockSums, dinv,
                                                           W1, W2, w1t, w2t);

    // 4. exclusive scan cnt2 -> rs (+ sentinel)
    scan_kernel<<<NB_SCAN2, 1024, 0, stream>>>(cnt2, blockSums, rs);

    // 5. fill CSR + GEMM1 (independent halves, overlapped in one dispatch)
    fill_gemm1_kernel<<<FILLB + GEMM1B, 256, 0, stream>>>(src, dst, rank, rs, csr_src,
                                                          x, w1t, dinv, h1b);

    // 6. fused: a1 = relu(b1 + dinv*gather(h1b));  h2b = bf16(dinv * (a1 @ W2))
    agg1_gemm2_fused<<<N_NODES / 16, 256, 0, stream>>>(csr_src, rs, dinv, b1, h1b, w2t, h2b);

    // 7. out = b2 + dinv * gather(h2b)
    agg2_kernel<<<(N_NODES + 3) / 4, 256, 0, stream>>>(csr_src, rs, dinv, b2, h2b, out);
}

// Round 16
// 204.673 us; speedup vs baseline: 1.0278x; 1.0123x over previous
//
#include <hip/hip_runtime.h>

#define N_NODES 50000
#define N_EDGES 800000
#define IN_DIM  128
#define HID_DIM 128
#define OUT_DIM 64

#define NPAD 50176                          // N_NODES rounded up
#define NB 7                                // src buckets of 8192 nodes (src>>13)
#define KEYS (N_NODES * NB)                 // 350000 composite (dst,bucket) keys
#define KPAD 350208                         // 342 * 1024
#define NB_SCAN2 (KPAD / 1024)              // 342
#define FILLB ((N_EDGES / 4 + 255) / 256)   // 782 fill blocks
#define GEMM1B ((N_NODES + 63) / 64)        // 782 gemm1 blocks
#define DINVB ((N_NODES + 1023) / 1024)     // 49 dinv blocks (1024 thr)

typedef __attribute__((ext_vector_type(8))) short bf16x8;   // 8 bf16 in 4 VGPRs
typedef __attribute__((ext_vector_type(4))) float f32x4;

// float -> bf16 (round-to-nearest-even), as ushort
__device__ __forceinline__ unsigned short f2bf(float f) {
    unsigned u = __float_as_uint(f);
    u += 0x7fffu + ((u >> 16) & 1u);
    return (unsigned short)(u >> 16);
}
// bf16 pair unpack from a uint (little-endian: low ushort first)
__device__ __forceinline__ float bflo(unsigned u) { return __uint_as_float(u << 16); }
__device__ __forceinline__ float bfhi(unsigned u) { return __uint_as_float(u & 0xffff0000u); }

// accumulate one uint4 (8 bf16) into acc[8]
#define ACC8(u)  do { \
    acc[0] += bflo(u.x); acc[1] += bfhi(u.x); \
    acc[2] += bflo(u.y); acc[3] += bfhi(u.y); \
    acc[4] += bflo(u.z); acc[5] += bfhi(u.z); \
    acc[6] += bflo(u.w); acc[7] += bfhi(u.w); } while (0)

// ---------------- dispatch 2: rank+histogram, 1 edge/thread ----------------
// depth-1 atomic chains: 800k independent atomics (r15 measured win vs depth-4).

__global__ void rank_hist_kernel(const int* __restrict__ src, const int* __restrict__ dst,
                                 int* __restrict__ cnt2, int* __restrict__ rank) {
    int e = blockIdx.x * 256 + threadIdx.x;
    if (e >= N_EDGES) return;
    int s = src[e], d = dst[e];
    rank[e] = atomicAdd(&cnt2[d * NB + (s >> 13)], 1);
}

// ---------------- dispatch 3: single-pass lookback scan + dinv + W^T prep ----------
// Scan blocks publish their total (atomicExch, value+1 as ready flag) BEFORE any
// spin -> all publishes complete unconditionally; 342+55 blocks < 512 co-resident
// capacity (2 blocks/CU @ 1024thr) -> spins always resolve. Payload rides in the
// atomic value itself (no fence needed).

__global__ __launch_bounds__(1024) void scan_all_kernel(const int* __restrict__ cnt2,
                                                        int* __restrict__ partials,
                                                        int* __restrict__ rs,
                                                        float* __restrict__ dinv,
                                                        const float* __restrict__ W1,
                                                        const float* __restrict__ W2,
                                                        unsigned short* __restrict__ w1t,
                                                        unsigned short* __restrict__ w2t) {
    int bid = blockIdx.x;
    int tid = threadIdx.x;
    if (bid < NB_SCAN2) {
        __shared__ int s[1024];
        __shared__ int p[1024];
        int i = bid * 1024 + tid;
        int v = (i < KEYS) ? cnt2[i] : 0;
        s[tid] = v;
        __syncthreads();
        for (int off = 1; off < 1024; off <<= 1) {
            int t = (tid >= off) ? s[tid - off] : 0;
            __syncthreads();
            s[tid] += t;
            __syncthreads();
        }
        // publish own total first (unconditional -> deadlock-free)
        if (tid == 0) atomicExch(&partials[bid], s[1023] + 1);
        if (bid == 0 && tid == 0) rs[KEYS] = N_EDGES;    // sentinel
        // lookback: thread tid waits on predecessor tid's slot
        int myp = 0;
        if (tid < bid) {
            int val;
            do { val = atomicAdd(&partials[tid], 0); } while (val == 0);
            myp = val - 1;
        }
        p[tid] = myp;
        __syncthreads();
        for (int off = 512; off > 0; off >>= 1) {
            if (tid < off) p[tid] += p[tid + off];
            __syncthreads();
        }
        if (i < KEYS) rs[i] = p[0] + s[tid] - v;         // exclusive prefix
    } else if (bid < NB_SCAN2 + DINVB) {
        int d = (bid - NB_SCAN2) * 1024 + tid;
        if (d < N_NODES) {
            int base = d * NB;
            int deg = cnt2[base] + cnt2[base + 1] + cnt2[base + 2] + cnt2[base + 3]
                    + cnt2[base + 4] + cnt2[base + 5] + cnt2[base + 6];
            dinv[d] = (deg > 0) ? rsqrtf((float)deg) : 0.0f;
        }
    } else if (bid < NB_SCAN2 + DINVB + 4) {
        // W1T[c][k] = bf16(W1[k][c]); 128x128 -> 4096 ushort4
        int idx = (bid - NB_SCAN2 - DINVB) * 1024 + tid;
        int c = idx >> 5, k4 = (idx & 31) * 4;
        ushort4 o;
        o.x = f2bf(W1[(k4 + 0) * 128 + c]);
        o.y = f2bf(W1[(k4 + 1) * 128 + c]);
        o.z = f2bf(W1[(k4 + 2) * 128 + c]);
        o.w = f2bf(W1[(k4 + 3) * 128 + c]);
        *(ushort4*)(w1t + c * 128 + k4) = o;
    } else {
        // W2T[c][k] = bf16(W2[k][c]); 64x128 -> 2048 ushort4 (2 blocks exactly)
        int idx = (bid - NB_SCAN2 - DINVB - 4) * 1024 + tid;
        int c = idx >> 5, k4 = (idx & 31) * 4;
        ushort4 o;
        o.x = f2bf(W2[(k4 + 0) * 64 + c]);
        o.y = f2bf(W2[(k4 + 1) * 64 + c]);
        o.z = f2bf(W2[(k4 + 2) * 64 + c]);
        o.w = f2bf(W2[(k4 + 3) * 64 + c]);
        *(ushort4*)(w2t + c * 128 + k4) = o;
    }
}

// ---------------- dispatch 4: fill CSR + GEMM1 (independent -> overlapped) --------

__global__ __launch_bounds__(256) void fill_gemm1_kernel(const int* __restrict__ src,
                                                         const int* __restrict__ dst,
                                                         const int* __restrict__ rank,
                                                         const int* __restrict__ rs,
                                                         int* __restrict__ csr_src,
                                                         const float* __restrict__ x,
                                                         const unsigned short* __restrict__ w1t,
                                                         const float* __restrict__ dinv,
                                                         unsigned short* __restrict__ h1b) {
    int bid = blockIdx.x;
    if (bid < FILLB) {
        int e = (bid * 256 + threadIdx.x) * 4;
        if (e >= N_EDGES) return;
        int4 s4 = *(const int4*)(src + e);
        int4 d4 = *(const int4*)(dst + e);
        int4 r4 = *(const int4*)(rank + e);
        csr_src[rs[d4.x * NB + (s4.x >> 13)] + r4.x] = s4.x;
        csr_src[rs[d4.y * NB + (s4.y >> 13)] + r4.y] = s4.y;
        csr_src[rs[d4.z * NB + (s4.z >> 13)] + r4.z] = s4.z;
        csr_src[rs[d4.w * NB + (s4.w >> 13)] + r4.w] = s4.w;
        return;
    }

    // ---- GEMM1 (MFMA, inline fp32->bf16 A-cast): h1b = bf16(dinv * (x @ W1)) ----
    int gb = bid - FILLB;
    int wave = threadIdx.x >> 6;
    int lane = threadIdx.x & 63;
    int n = lane & 15, quad = lane >> 4;
    int row0 = gb * 64 + wave * 16;

    int arow = row0 + n;
    if (arow >= N_NODES) arow = N_NODES - 1;             // clamp (stores guarded)
    const float* aptr = x + (size_t)arow * 128 + quad * 8;
    const unsigned short* bbase = w1t + (size_t)n * 128 + quad * 8;

    f32x4 acc[8];
#pragma unroll
    for (int t = 0; t < 8; ++t) acc[t] = (f32x4){0.f, 0.f, 0.f, 0.f};

#pragma unroll
    for (int w4 = 0; w4 < 4; ++w4) {
        float4 f0 = *(const float4*)(aptr + w4 * 32);
        float4 f1 = *(const float4*)(aptr + w4 * 32 + 4);
        bf16x8 af;
        af[0] = (short)f2bf(f0.x); af[1] = (short)f2bf(f0.y);
        af[2] = (short)f2bf(f0.z); af[3] = (short)f2bf(f0.w);
        af[4] = (short)f2bf(f1.x); af[5] = (short)f2bf(f1.y);
        af[6] = (short)f2bf(f1.z); af[7] = (short)f2bf(f1.w);
#pragma unroll
        for (int t = 0; t < 8; ++t) {
            bf16x8 bf = *(const bf16x8*)(bbase + (size_t)t * 2048 + w4 * 32);
            acc[t] = __builtin_amdgcn_mfma_f32_16x16x32_bf16(af, bf, acc[t], 0, 0, 0);
        }
    }

#pragma unroll
    for (int r = 0; r < 4; ++r) {
        int row = row0 + quad * 4 + r;
        if (row < N_NODES) {
            float dn = dinv[row];
            unsigned short* o = h1b + (size_t)row * 128 + n;
#pragma unroll
            for (int t = 0; t < 8; ++t) o[t * 16] = f2bf(acc[t][r] * dn);
        }
    }
}

// ---------------- dispatch 5: fused agg1 + GEMM2 (r10 shape) ----------------

#define A1T_STRIDE 136

__global__ __launch_bounds__(256) void agg1_gemm2_fused(const int* __restrict__ csr_src,
                                                        const int* __restrict__ rs,
                                                        const float* __restrict__ dinv,
                                                        const float* __restrict__ b1,
                                                        const unsigned short* __restrict__ h1b,
                                                        const unsigned short* __restrict__ w2t,
                                                        unsigned short* __restrict__ h2b) {
    __shared__ unsigned short a1t[16 * A1T_STRIDE];      // 16 x 128 bf16, padded

    int node0 = blockIdx.x * 16;
    int g = threadIdx.x >> 4;        // node within block
    int q = threadIdx.x & 15;        // uint4 slot (channels 8q..8q+7)
    int node = node0 + g;            // always < N_NODES (50000 = 3125*16)
    int start = rs[node * NB];
    int m = rs[node * NB + NB] - start;   // sentinel rs[KEYS] covers node = N-1

    float acc[8] = {};
    int j = 0;
    for (; j + 3 < m; j += 4) {
        int s0 = csr_src[start + j];
        int s1 = csr_src[start + j + 1];
        int s2 = csr_src[start + j + 2];
        int s3 = csr_src[start + j + 3];
        uint4 u0 = ((const uint4*)(h1b + (size_t)s0 * 128))[q];
        uint4 u1 = ((const uint4*)(h1b + (size_t)s1 * 128))[q];
        uint4 u2 = ((const uint4*)(h1b + (size_t)s2 * 128))[q];
        uint4 u3 = ((const uint4*)(h1b + (size_t)s3 * 128))[q];
        ACC8(u0); ACC8(u1); ACC8(u2); ACC8(u3);
    }
    for (; j < m; ++j) {
        int s0 = csr_src[start + j];
        uint4 u0 = ((const uint4*)(h1b + (size_t)s0 * 128))[q];
        ACC8(u0);
    }

    {
        float dn = dinv[node];
        float4 bA = ((const float4*)b1)[2 * q];
        float4 bB = ((const float4*)b1)[2 * q + 1];
        ushort4 oA, oB;
        oA.x = f2bf(fmaxf(acc[0] * dn + bA.x, 0.f));
        oA.y = f2bf(fmaxf(acc[1] * dn + bA.y, 0.f));
        oA.z = f2bf(fmaxf(acc[2] * dn + bA.z, 0.f));
        oA.w = f2bf(fmaxf(acc[3] * dn + bA.w, 0.f));
        oB.x = f2bf(fmaxf(acc[4] * dn + bB.x, 0.f));
        oB.y = f2bf(fmaxf(acc[5] * dn + bB.y, 0.f));
        oB.z = f2bf(fmaxf(acc[6] * dn + bB.z, 0.f));
        oB.w = f2bf(fmaxf(acc[7] * dn + bB.w, 0.f));
        ushort4* o = (ushort4*)(a1t + g * A1T_STRIDE + q * 8);
        o[0] = oA;
        o[1] = oB;
    }
    __syncthreads();

    // Phase 2: MFMA 16 rows x 16 cols per wave
    int wave = threadIdx.x >> 6;
    int lane = threadIdx.x & 63;
    int n = lane & 15, quad = lane >> 4;
    const unsigned short* bbase = w2t + (size_t)(wave * 16 + n) * 128 + quad * 8;
    const unsigned short* abase = a1t + (size_t)n * A1T_STRIDE + quad * 8;

    f32x4 c2 = (f32x4){0.f, 0.f, 0.f, 0.f};
#pragma unroll
    for (int w4 = 0; w4 < 4; ++w4) {
        bf16x8 af = *(const bf16x8*)(abase + w4 * 32);
        bf16x8 bf = *(const bf16x8*)(bbase + w4 * 32);
        c2 = __builtin_amdgcn_mfma_f32_16x16x32_bf16(af, bf, c2, 0, 0, 0);
    }

#pragma unroll
    for (int r = 0; r < 4; ++r) {
        int row = node0 + quad * 4 + r;
        float dn = dinv[row];
        h2b[(size_t)row * 64 + wave * 16 + n] = f2bf(c2[r] * dn);
    }
}

// ---------------- dispatch 6: agg2: out[n] = b2 + dinv[n] * sum h2b[src_e] ----------

__global__ __launch_bounds__(256) void agg2_kernel(const int* __restrict__ csr_src,
                                                   const int* __restrict__ rs,
                                                   const float* __restrict__ dinv,
                                                   const float* __restrict__ b2,
                                                   const unsigned short* __restrict__ h2b,
                                                   float* __restrict__ out) {
    int node = blockIdx.x * 4 + (threadIdx.x >> 6);
    if (node >= N_NODES) return;
    int lane = threadIdx.x & 63;
    int grp = lane >> 3;         // 8 groups: edge j = grp + 8t
    int q   = lane & 7;          // uint4 slot (channels 8q..8q+7)
    int start = rs[node * NB];
    int m = rs[node * NB + NB] - start;

    float acc[8] = {};

    int j = grp;
    for (; j + 8 < m; j += 16) {
        int s0 = csr_src[start + j];
        int s1 = csr_src[start + j + 8];
        uint4 u0 = ((const uint4*)(h2b + (size_t)s0 * 64))[q];
        uint4 u1 = ((const uint4*)(h2b + (size_t)s1 * 64))[q];
        ACC8(u0); ACC8(u1);
    }
    if (j < m) {
        int s0 = csr_src[start + j];
        uint4 u0 = ((const uint4*)(h2b + (size_t)s0 * 64))[q];
        ACC8(u0);
    }

#pragma unroll
    for (int d = 8; d <= 32; d <<= 1) {
#pragma unroll
        for (int c = 0; c < 8; ++c) acc[c] += __shfl_xor(acc[c], d, 64);
    }

    if (lane < 8) {
        float dn = dinv[node];
        float4 bA = ((const float4*)b2)[2 * q];
        float4 bB = ((const float4*)b2)[2 * q + 1];
        float4 rA, rB;
        rA.x = acc[0] * dn + bA.x;
        rA.y = acc[1] * dn + bA.y;
        rA.z = acc[2] * dn + bA.z;
        rA.w = acc[3] * dn + bA.w;
        rB.x = acc[4] * dn + bB.x;
        rB.y = acc[5] * dn + bB.y;
        rB.z = acc[6] * dn + bB.z;
        rB.w = acc[7] * dn + bB.w;
        float4* o = (float4*)(out + (size_t)node * 64);
        o[2 * q] = rA;
        o[2 * q + 1] = rB;
    }
}

// ---------------- launch ----------------

extern "C" void kernel_launch(void* const* d_in, const int* in_sizes, int n_in,
                              void* d_out, int out_size, void* d_ws, size_t ws_size,
                              hipStream_t stream) {
    const float* x  = (const float*)d_in[0];
    const int*   ei = (const int*)d_in[1];       // [2, E]: src = ei[0..E), dst = ei[E..2E)
    const float* W1 = (const float*)d_in[2];
    const float* b1 = (const float*)d_in[3];
    const float* W2 = (const float*)d_in[4];
    const float* b2 = (const float*)d_in[5];
    float* out = (float*)d_out;

    const int* src = ei;
    const int* dst = ei + N_EDGES;

    // workspace layout (16B-aligned regions)
    char* ws = (char*)d_ws;
    int*   cnt2      = (int*)ws;                                 // KPAD
    int*   partials  = cnt2 + KPAD;                              // 512 (zeroed w/ cnt2)
    int*   rs        = partials + 512;                           // KEYS+1 (pad to KPAD)
    float* dinv      = (float*)(rs + KPAD);                      // NPAD
    int*   rank      = (int*)(dinv + NPAD);                      // N_EDGES
    int*   csr_src   = rank + N_EDGES;                           // N_EDGES
    unsigned short* h1b = (unsigned short*)(csr_src + N_EDGES);  // 50000*128 bf16
    unsigned short* h2b = h1b + (size_t)N_NODES * HID_DIM;       // 50000*64 bf16
    unsigned short* w1t = h2b + (size_t)N_NODES * OUT_DIM;       // 128*128 bf16
    unsigned short* w2t = w1t + 128 * 128;                       // 64*128 bf16

    // 1. zero cnt2 + partials (adjacent -> one memset)
    hipMemsetAsync(cnt2, 0, (KPAD + 512) * sizeof(int), stream);

    // 2. rank+histogram, 1 edge/thread (depth-1 atomic chains)
    rank_hist_kernel<<<(N_EDGES + 255) / 256, 256, 0, stream>>>(src, dst, cnt2, rank);

    // 3. single-pass lookback scan + dinv + W1^T/W2^T prep (one dispatch)
    scan_all_kernel<<<NB_SCAN2 + DINVB + 6, 1024, 0, stream>>>(cnt2, partials, rs, dinv,
                                                               W1, W2, w1t, w2t);

    // 4. fill CSR + GEMM1 (independent halves, overlapped in one dispatch)
    fill_gemm1_kernel<<<FILLB + GEMM1B, 256, 0, stream>>>(src, dst, rank, rs, csr_src,
                                                          x, w1t, dinv, h1b);

    // 5. fused: a1 = relu(b1 + dinv*gather(h1b));  h2b = bf16(dinv * (a1 @ W2))
    agg1_gemm2_fused<<<N_NODES / 16, 256, 0, stream>>>(csr_src, rs, dinv, b1, h1b, w2t, h2b);

    // 6. out = b2 + dinv * gather(h2b)
    agg2_kernel<<<(N_NODES + 3) / 4, 256, 0, stream>>>(csr_src, rs, dinv, b2, h2b, out);
}